// Round 6
// baseline (5240.439 us; speedup 1.0000x reference)
//
#include <hip/hip_runtime.h>

#define NN   50000
#define NE   1600000
#define CIN  512
#define CCAP 16384
#define IN_STR 96     // fixed-stride in-edge buckets (P(in-deg>96) ~ 0 for Poisson(32))
#define E_STR  72     // compacted earlier-neighbor list stride
#define OVF   (1 << 30)

#define ST_UNK 0
#define ST_CEN 1
#define ST_REM 2

typedef unsigned long long u64;

// earlier(u,v): u precedes v in greedy order = (z desc, idx asc); f64 z (validated in round 3)
__device__ __forceinline__ bool earlier_f(double zu, int u, double zv, int v) {
    return (zu > zv) || (zu == zv && u < v);
}

// K1: per-node f64 dots p = x.w_rel, z = x.w_root + b. One wave per row.
__global__ __launch_bounds__(256) void k_rowdots(const float* __restrict__ x,
                                                 const float* __restrict__ wrel,
                                                 const float* __restrict__ wroot,
                                                 const float* __restrict__ bptr,
                                                 double* __restrict__ p,
                                                 double* __restrict__ z) {
    int wave = (blockIdx.x * blockDim.x + threadIdx.x) >> 6;
    int lane = threadIdx.x & 63;
    if (wave >= NN) return;
    const float4* xr = (const float4*)(x + (size_t)wave * CIN);
    const float4* wr = (const float4*)wrel;
    const float4* wo = (const float4*)wroot;
    double pd = 0.0, qd = 0.0;
    int i0 = lane * 2;
#pragma unroll
    for (int k = 0; k < 2; ++k) {
        float4 xv = xr[i0 + k];
        float4 wv = wr[i0 + k];
        float4 ov = wo[i0 + k];
        pd += (double)xv.x * wv.x + (double)xv.y * wv.y + (double)xv.z * wv.z + (double)xv.w * wv.w;
        qd += (double)xv.x * ov.x + (double)xv.y * ov.y + (double)xv.z * ov.z + (double)xv.w * ov.w;
    }
    for (int off = 32; off > 0; off >>= 1) {
        pd += __shfl_down(pd, off);
        qd += __shfl_down(qd, off);
    }
    if (lane == 0) {
        p[wave] = pd;
        z[wave] = qd + (double)bptr[0];
    }
}

// K2: scatter in-edge sources into fixed-stride buckets; cnt doubles as in-degree.
__global__ __launch_bounds__(256) void k_scatter(const int* __restrict__ src, const int* __restrict__ dst,
                                                 int* __restrict__ cnt, int* __restrict__ inSrc) {
    int e = blockIdx.x * blockDim.x + threadIdx.x;
    if (e < NE) {
        int t = dst[e];
        if (t >= 0 && t < NN) {
            int pos = atomicAdd(&cnt[t], 1);
            if (pos < IN_STR) inSrc[(size_t)t * IN_STR + pos] = src[e];
        }
    }
}

// K3: z[v] += sum of p over in-edge sources (f64)
__global__ __launch_bounds__(256) void k_zacc(double* __restrict__ z, const double* __restrict__ p,
                                              const int* __restrict__ cnt, const int* __restrict__ inSrc) {
    int v = blockIdx.x * blockDim.x + threadIdx.x;
    if (v >= NN) return;
    int deg = min(cnt[v], IN_STR);
    size_t b = (size_t)v * IN_STR;
    double acc = z[v];
    for (int i = 0; i < deg; ++i) acc += p[inSrc[b + i]];
    z[v] = acc;
}

// K5: compact earlier-neighbor lists (only deps that matter for the greedy state)
__global__ __launch_bounds__(256) void k_prep(const double* __restrict__ z, const int* __restrict__ cnt,
                                              const int* __restrict__ inSrc,
                                              int* __restrict__ eNbr, int* __restrict__ eCnt) {
    int v = blockIdx.x * blockDim.x + threadIdx.x;
    if (v >= NN) return;
    double zv = z[v];
    int deg = min(cnt[v], IN_STR);
    size_t b = (size_t)v * IN_STR;
    size_t eb = (size_t)v * E_STR;
    int c = 0;
    bool ovf = false;
    for (int i = 0; i < deg; ++i) {
        int u = inSrc[b + i];
        if (earlier_f(z[u], u, zv, v)) {
            if (c < E_STR) eNbr[eb + c] = u;
            else ovf = true;
            ++c;
        }
    }
    eCnt[v] = ovf ? OVF : c;
}

// K6: bounded RMW spin (atomic RMWs are device-scope coherent; never guesses on expiry).
__global__ __launch_bounds__(256) void k_fix_spin(const double* __restrict__ z,
                                                  const int* __restrict__ cnt, const int* __restrict__ inSrc,
                                                  int* __restrict__ eNbr, int* __restrict__ eCnt,
                                                  int* state) {
    int v = blockIdx.x * blockDim.x + threadIdx.x;
    if (v >= NN) return;
    int c = eCnt[v];
    if (c >= OVF) {  // rare overflow path: full rescan each poll
        double zv = z[v];
        int deg = min(cnt[v], IN_STR);
        size_t b = (size_t)v * IN_STR;
        for (int it = 0; it < 256; ++it) {
            bool unk = false, rem = false;
            for (int i = 0; i < deg; ++i) {
                int u = inSrc[b + i];
                if (earlier_f(z[u], u, zv, v)) {
                    int st = atomicOr(&state[u], 0);
                    if (st == ST_CEN) { rem = true; break; }
                    if (st == ST_UNK) unk = true;
                }
            }
            if (rem) { atomicExch(&state[v], ST_REM); return; }
            if (!unk) { atomicExch(&state[v], ST_CEN); return; }
            __builtin_amdgcn_s_sleep(1);
        }
        return;
    }
    size_t eb = (size_t)v * E_STR;
    for (int it = 0; it < 256; ++it) {
        int j = 0;
        bool rem = false;
        while (j < c) {
            int u = eNbr[eb + j];
            int st = atomicOr(&state[u], 0);
            if (st == ST_CEN) { rem = true; break; }
            if (st == ST_REM) { eNbr[eb + j] = eNbr[eb + c - 1]; --c; }  // prune resolved
            else ++j;
        }
        if (rem) { atomicExch(&state[v], ST_REM); return; }
        if (c == 0) { atomicExch(&state[v], ST_CEN); return; }
        __builtin_amdgcn_s_sleep(1);
    }
    eCnt[v] = c;  // hand pruned list to the ladder; leave ST_UNK (never guess)
}

// K7: one deterministic sweep per launch (plain ops; launch boundary = visibility).
// Each launch resolves >= 1 dependency level; ladder 112 > depth bound ~100.
__global__ __launch_bounds__(256) void k_fix_sweep(const double* __restrict__ z,
                                                   const int* __restrict__ cnt, const int* __restrict__ inSrc,
                                                   int* __restrict__ eNbr, int* __restrict__ eCnt,
                                                   int* __restrict__ state) {
    int v = blockIdx.x * blockDim.x + threadIdx.x;
    if (v >= NN) return;
    if (state[v] != ST_UNK) return;   // gate: converged sweeps cost ~1 coalesced load
    int c = eCnt[v];
    if (c >= OVF) {
        double zv = z[v];
        int deg = min(cnt[v], IN_STR);
        size_t b = (size_t)v * IN_STR;
        bool unk = false, rem = false;
        for (int i = 0; i < deg; ++i) {
            int u = inSrc[b + i];
            if (earlier_f(z[u], u, zv, v)) {
                int st = state[u];
                if (st == ST_CEN) { rem = true; break; }
                if (st == ST_UNK) unk = true;
            }
        }
        if (rem) state[v] = ST_REM;
        else if (!unk) state[v] = ST_CEN;
        return;
    }
    size_t eb = (size_t)v * E_STR;
    int j = 0;
    bool rem = false;
    while (j < c) {
        int u = eNbr[eb + j];
        int st = state[u];
        if (st == ST_CEN) { rem = true; break; }
        if (st == ST_REM) { eNbr[eb + j] = eNbr[eb + c - 1]; --c; }
        else ++j;
    }
    if (rem) state[v] = ST_REM;
    else if (c == 0) state[v] = ST_CEN;
    else eCnt[v] = c;
}

__global__ __launch_bounds__(256) void k_compact(const int* __restrict__ state, const double* __restrict__ z,
                                                 double* __restrict__ cz, int* __restrict__ cidx,
                                                 int* counters) {
    int v = blockIdx.x * blockDim.x + threadIdx.x;
    if (v >= NN) return;
    if (state[v] == ST_CEN) {
        int slot = atomicAdd(&counters[0], 1);
        if (slot < CCAP) { cz[slot] = z[v]; cidx[slot] = v; }
    }
}

// Rank centers by (z desc, idx asc) via O(C^2) LDS-tiled counting.
__global__ __launch_bounds__(256) void k_rank(const double* __restrict__ cz, const int* __restrict__ cidx,
                                              const int* __restrict__ counters, int* __restrict__ cidOfNode) {
    __shared__ double tz[2048];
    __shared__ int ti[2048];
    int C = counters[0];
    if (C > CCAP) C = CCAP;
    int g = blockIdx.x * blockDim.x + threadIdx.x;
    bool mine = (g < C);
    double myz = 0.0;
    int myi = 0;
    if (mine) { myz = cz[g]; myi = cidx[g]; }
    int r = 0;
    for (int base = 0; base < C; base += 2048) {
        int tile = min(2048, C - base);
        for (int t = threadIdx.x; t < tile; t += blockDim.x) { tz[t] = cz[base + t]; ti[t] = cidx[base + t]; }
        __syncthreads();
        if (mine) {
            for (int t = 0; t < tile; ++t)
                if (earlier_f(tz[t], ti[t], myz, myi)) ++r;
        }
        __syncthreads();
    }
    if (mine && myi >= 0 && myi < NN) cidOfNode[myi] = r;
}

// Final cluster = latest-ranked center touching u (incl. self): min (z,idx)-order key.
__global__ __launch_bounds__(256) void k_assign(const int* __restrict__ state, const double* __restrict__ z,
                                                const int* __restrict__ cnt, const int* __restrict__ inSrc,
                                                const int* __restrict__ cidOfNode, const int* __restrict__ batch,
                                                float* __restrict__ out_cl,
                                                float* __restrict__ out_ce, float* __restrict__ out_nb,
                                                int* __restrict__ mCount) {
    int u = blockIdx.x * blockDim.x + threadIdx.x;
    if (u >= NN) return;
    bool have = false;
    double bz = 0.0;
    int bi = -1;
    int stu = state[u];
    if (stu == ST_CEN) { have = true; bz = z[u]; bi = u; }
    int deg = min(cnt[u], IN_STR);
    size_t b = (size_t)u * IN_STR;
    for (int i = 0; i < deg; ++i) {
        int w = inSrc[b + i];
        if (state[w] != ST_CEN) continue;
        double zw = z[w];
        // later in greedy order = earlier_f(bz,bi, zw,w), i.e. current best precedes w
        if (!have || earlier_f(bz, bi, zw, w)) { have = true; bz = zw; bi = w; }
    }
    int cl = have ? cidOfNode[bi] : 0;
    if (cl < 0) cl = 0;
    if (cl >= CCAP) cl = CCAP - 1;
    out_cl[u] = (float)cl;
    out_ce[u] = (stu == ST_CEN) ? 1.0f : 0.0f;
    out_nb[cl] = (float)batch[u];  // batch all-zero; benign same-value race
    atomicAdd(&mCount[cl], 1);
}

__global__ __launch_bounds__(1024) void k_scan(const int* __restrict__ in, int* __restrict__ out,
                                               int* __restrict__ cur, int n) {
    __shared__ int wsum[16];
    __shared__ int wpre[16];
    int tid = threadIdx.x, lane = tid & 63, wid = tid >> 6;
    int running = 0;
    for (int base = 0; base < n; base += 1024) {
        int i = base + tid;
        int v = (i < n) ? in[i] : 0;
        int incl = v;
        for (int off = 1; off < 64; off <<= 1) {
            int t = __shfl_up(incl, off);
            if (lane >= off) incl += t;
        }
        if (lane == 63) wsum[wid] = incl;
        __syncthreads();
        if (wid == 0 && lane < 16) {
            int s = wsum[lane];
            for (int off = 1; off < 16; off <<= 1) {
                int t = __shfl_up(s, off);
                if (lane >= off) s += t;
            }
            wpre[lane] = s - wsum[lane];
        }
        __syncthreads();
        int excl = running + wpre[wid] + incl - v;
        if (i < n) { out[i] = excl; if (cur) cur[i] = excl; }
        int tot = wpre[15] + wsum[15];
        running += tot;
        __syncthreads();
    }
    if (tid == 0) out[n] = running;
}

__global__ __launch_bounds__(256) void k_members(const float* __restrict__ out_cl, int* __restrict__ mCursor,
                                                 int* __restrict__ members) {
    int u = blockIdx.x * blockDim.x + threadIdx.x;
    if (u < NN) {
        int cl = (int)out_cl[u];
        if (cl < 0) cl = 0;
        if (cl >= CCAP) cl = CCAP - 1;
        int pos = atomicAdd(&mCursor[cl], 1);
        if (pos >= 0 && pos < NN) members[pos] = u;
    }
}

__global__ __launch_bounds__(256) void k_newx(const float* __restrict__ x, const int* __restrict__ mStart,
                                              const int* __restrict__ members, const int* __restrict__ counters,
                                              float* __restrict__ out_x) {
    int b = blockIdx.x;
    int t = threadIdx.x;
    int C = counters[0];
    if (C > CCAP) C = CCAP;
    double a0 = 0.0, a1 = 0.0;
    if (b < C) {
        int s = mStart[b], e = mStart[b + 1];
        for (int m = s; m < e; ++m) {
            const float* row = x + (size_t)members[m] * CIN;
            a0 += (double)row[t];
            a1 += (double)row[t + 256];
        }
    }
    out_x[(size_t)b * CIN + t] = (float)a0;
    out_x[(size_t)b * CIN + t + 256] = (float)a1;
}

__global__ __launch_bounds__(256) void k_edges(const int* __restrict__ src, const int* __restrict__ dst,
                                               const float* __restrict__ attr, const float* __restrict__ out_cl,
                                               float* __restrict__ out_ei, float* __restrict__ out_at) {
    int e = blockIdx.x * blockDim.x + threadIdx.x;
    if (e >= NE) return;
    int s = src[e], d = dst[e];
    float cs = (s >= 0 && s < NN) ? out_cl[s] : 0.0f;
    float cd = (d >= 0 && d < NN) ? out_cl[d] : 0.0f;
    out_ei[e] = cs;
    out_ei[NE + e] = cd;
    out_at[e] = attr[e];
}

__global__ void k_final(const int* counters, float* out_nc) {
    if (threadIdx.x == 0 && blockIdx.x == 0) {
        int C = counters[0];
        if (C > CCAP) C = CCAP;
        out_nc[0] = (float)C;
    }
}

extern "C" void kernel_launch(void* const* d_in, const int* in_sizes, int n_in,
                              void* d_out, int out_size, void* d_ws, size_t ws_size,
                              hipStream_t stream) {
    const float* x = (const float*)d_in[0];
    const int* ei = (const int*)d_in[1];
    const float* ea = (const float*)d_in[2];
    const int* batch = (const int*)d_in[3];
    const float* wrel = (const float*)d_in[4];
    const float* wroot = (const float*)d_in[5];
    const float* bptr = (const float*)d_in[6];
    float* out = (float*)d_out;
    (void)d_ws; (void)ws_size; (void)in_sizes; (void)n_in; (void)out_size;

    const int* src = ei;
    const int* dst = ei + NE;

    float* out_x = out;                                 // 25,600,000
    float* out_ei = out + (size_t)NN * CIN;             // 3,200,000
    float* out_at = out_ei + 2 * (size_t)NE;            // 1,600,000
    float* out_nb = out_at + (size_t)NE;                // 50,000
    float* out_cl = out_nb + NN;                        // 50,000
    float* out_ce = out_cl + NN;                        // 50,000
    float* out_nc = out_ce + NN;                        // 1

    // Scratch region 1: inside out_x (102.4 MB); all dead before k_newx overwrites it.
    char* r1 = (char*)out_x;
    size_t off1 = 0;
    auto alloc1 = [&](size_t bytes) -> void* {
        void* ptr = (void*)(r1 + off1);
        off1 = (off1 + bytes + 255) & ~(size_t)255;
        return ptr;
    };
    double* p_ = (double*)alloc1(NN * 8);
    double* z_ = (double*)alloc1(NN * 8);
    double* cz = (double*)alloc1(CCAP * 8);
    int* cnt = (int*)alloc1(NN * 4);
    int* state = (int*)alloc1(NN * 4);
    int* cidOfNode = (int*)alloc1(NN * 4);
    int* cidx = (int*)alloc1(CCAP * 4);
    int* eCnt = (int*)alloc1(NN * 4);
    int* inSrc = (int*)alloc1((size_t)NN * IN_STR * 4);  // 19.2 MB
    int* eNbr = (int*)alloc1((size_t)NN * E_STR * 4);    // 14.4 MB (total ~36 MB < 102 MB)

    // Scratch region 2: inside out_at (6.4 MB); dead before k_edges (last) overwrites it.
    char* r2 = (char*)out_at;
    size_t off2 = 0;
    auto alloc2 = [&](size_t bytes) -> void* {
        void* ptr = (void*)(r2 + off2);
        off2 = (off2 + bytes + 255) & ~(size_t)255;
        return ptr;
    };
    int* members = (int*)alloc2(NN * 4);
    int* mCount = (int*)alloc2(CCAP * 4);
    int* mStart = (int*)alloc2((CCAP + 1) * 4);
    int* mCursor = (int*)alloc2(CCAP * 4);
    int* counters = (int*)alloc2(64);

    hipMemsetAsync(cnt, 0, NN * 4, stream);
    hipMemsetAsync(state, 0, NN * 4, stream);
    hipMemsetAsync(mCount, 0, CCAP * 4, stream);
    hipMemsetAsync(counters, 0, 64, stream);
    hipMemsetAsync(out_nb, 0, NN * 4, stream);

    const int TB = 256;
    const int GN = (NN + TB - 1) / TB;   // 196
    const int GE = (NE + TB - 1) / TB;   // 6250

    k_rowdots<<<(NN * 64 + TB - 1) / TB, TB, 0, stream>>>(x, wrel, wroot, bptr, p_, z_);
    k_scatter<<<GE, TB, 0, stream>>>(src, dst, cnt, inSrc);
    k_zacc<<<GN, TB, 0, stream>>>(z_, p_, cnt, inSrc);
    k_prep<<<GN, TB, 0, stream>>>(z_, cnt, inSrc, eNbr, eCnt);

    // Fixpoint: RMW-coherent spin (bounded, never guesses), then gated ladder.
    k_fix_spin<<<GN, TB, 0, stream>>>(z_, cnt, inSrc, eNbr, eCnt, state);
    for (int r = 0; r < 112; ++r)
        k_fix_sweep<<<GN, TB, 0, stream>>>(z_, cnt, inSrc, eNbr, eCnt, state);

    k_compact<<<GN, TB, 0, stream>>>(state, z_, cz, cidx, counters);
    k_rank<<<CCAP / TB, TB, 0, stream>>>(cz, cidx, counters, cidOfNode);
    k_assign<<<GN, TB, 0, stream>>>(state, z_, cnt, inSrc, cidOfNode, batch,
                                    out_cl, out_ce, out_nb, mCount);
    k_scan<<<1, 1024, 0, stream>>>(mCount, mStart, mCursor, CCAP);
    k_members<<<GN, TB, 0, stream>>>(out_cl, mCursor, members);
    k_newx<<<NN, TB, 0, stream>>>(x, mStart, members, counters, out_x);   // kills region 1
    k_final<<<1, 64, 0, stream>>>(counters, out_nc);
    k_edges<<<GE, TB, 0, stream>>>(src, dst, ea, out_cl, out_ei, out_at); // kills region 2 (last)
}

// Round 7
// 1242.578 us; speedup vs baseline: 4.2174x; 4.2174x over previous
//
#include <hip/hip_runtime.h>

#define NN   50000
#define NE   1600000
#define CIN  512
#define CCAP 16384
#define IN_STR 96     // fixed-stride in-edge buckets (P(in-deg>96) ~ 0 for Poisson(32))
#define E_STR  72     // compacted earlier-neighbor list stride
#define OVF   (1 << 30)
#define N_SWEEP 120   // > dependency-depth bound ~95 w.h.p.

#define ST_UNK 0
#define ST_CEN 1
#define ST_REM 2

// earlier(u,v): u precedes v in greedy order = (z desc, idx asc); f64 z (validated rounds 3/6)
__device__ __forceinline__ bool earlier_f(double zu, int u, double zv, int v) {
    return (zu > zv) || (zu == zv && u < v);
}

// K1: per-node f64 dots p = x.w_rel, z = x.w_root + b. One wave per row.
__global__ __launch_bounds__(256) void k_rowdots(const float* __restrict__ x,
                                                 const float* __restrict__ wrel,
                                                 const float* __restrict__ wroot,
                                                 const float* __restrict__ bptr,
                                                 double* __restrict__ p,
                                                 double* __restrict__ z) {
    int wave = (blockIdx.x * blockDim.x + threadIdx.x) >> 6;
    int lane = threadIdx.x & 63;
    if (wave >= NN) return;
    const float4* xr = (const float4*)(x + (size_t)wave * CIN);
    const float4* wr = (const float4*)wrel;
    const float4* wo = (const float4*)wroot;
    double pd = 0.0, qd = 0.0;
    int i0 = lane * 2;
#pragma unroll
    for (int k = 0; k < 2; ++k) {
        float4 xv = xr[i0 + k];
        float4 wv = wr[i0 + k];
        float4 ov = wo[i0 + k];
        pd += (double)xv.x * wv.x + (double)xv.y * wv.y + (double)xv.z * wv.z + (double)xv.w * wv.w;
        qd += (double)xv.x * ov.x + (double)xv.y * ov.y + (double)xv.z * ov.z + (double)xv.w * ov.w;
    }
    for (int off = 32; off > 0; off >>= 1) {
        pd += __shfl_down(pd, off);
        qd += __shfl_down(qd, off);
    }
    if (lane == 0) {
        p[wave] = pd;
        z[wave] = qd + (double)bptr[0];
    }
}

// K2: scatter in-edge sources into fixed-stride buckets; cnt doubles as in-degree.
__global__ __launch_bounds__(256) void k_scatter(const int* __restrict__ src, const int* __restrict__ dst,
                                                 int* __restrict__ cnt, int* __restrict__ inSrc) {
    int e = blockIdx.x * blockDim.x + threadIdx.x;
    if (e < NE) {
        int t = dst[e];
        if (t >= 0 && t < NN) {
            int pos = atomicAdd(&cnt[t], 1);
            if (pos < IN_STR) inSrc[(size_t)t * IN_STR + pos] = src[e];
        }
    }
}

// K3: z[v] += sum of p over in-edge sources (f64)
__global__ __launch_bounds__(256) void k_zacc(double* __restrict__ z, const double* __restrict__ p,
                                              const int* __restrict__ cnt, const int* __restrict__ inSrc) {
    int v = blockIdx.x * blockDim.x + threadIdx.x;
    if (v >= NN) return;
    int deg = min(cnt[v], IN_STR);
    size_t b = (size_t)v * IN_STR;
    double acc = z[v];
    for (int i = 0; i < deg; ++i) acc += p[inSrc[b + i]];
    z[v] = acc;
}

// K4: compact earlier-neighbor lists (only deps that matter for the greedy state)
__global__ __launch_bounds__(256) void k_prep(const double* __restrict__ z, const int* __restrict__ cnt,
                                              const int* __restrict__ inSrc,
                                              int* __restrict__ eNbr, int* __restrict__ eCnt) {
    int v = blockIdx.x * blockDim.x + threadIdx.x;
    if (v >= NN) return;
    double zv = z[v];
    int deg = min(cnt[v], IN_STR);
    size_t b = (size_t)v * IN_STR;
    size_t eb = (size_t)v * E_STR;
    int c = 0;
    bool ovf = false;
    for (int i = 0; i < deg; ++i) {
        int u = inSrc[b + i];
        if (earlier_f(z[u], u, zv, v)) {
            if (c < E_STR) eNbr[eb + c] = u;
            else ovf = true;
            ++c;
        }
    }
    eCnt[v] = ovf ? OVF : c;
}

// K5: one deterministic sweep per launch (plain ops; kernel boundary = coherence).
// Each launch resolves >= 1 dependency level; ladder N_SWEEP > depth bound ~95.
// Gated: resolved nodes cost one coalesced load. Lists self-prune across launches.
__global__ __launch_bounds__(256) void k_fix_sweep(const double* __restrict__ z,
                                                   const int* __restrict__ cnt, const int* __restrict__ inSrc,
                                                   int* __restrict__ eNbr, int* __restrict__ eCnt,
                                                   int* __restrict__ state) {
    int v = blockIdx.x * blockDim.x + threadIdx.x;
    if (v >= NN) return;
    if (state[v] != ST_UNK) return;
    int c = eCnt[v];
    if (c >= OVF) {   // rare overflow path: full rescan
        double zv = z[v];
        int deg = min(cnt[v], IN_STR);
        size_t b = (size_t)v * IN_STR;
        bool unk = false, rem = false;
        for (int i = 0; i < deg; ++i) {
            int u = inSrc[b + i];
            if (earlier_f(z[u], u, zv, v)) {
                int st = state[u];
                if (st == ST_CEN) { rem = true; break; }
                if (st == ST_UNK) unk = true;
            }
        }
        if (rem) state[v] = ST_REM;
        else if (!unk) state[v] = ST_CEN;
        return;
    }
    size_t eb = (size_t)v * E_STR;
    int j = 0;
    bool rem = false;
    while (j < c) {
        int u = eNbr[eb + j];
        int st = state[u];
        if (st == ST_CEN) { rem = true; break; }
        if (st == ST_REM) { eNbr[eb + j] = eNbr[eb + c - 1]; --c; }  // prune resolved
        else ++j;
    }
    if (rem) state[v] = ST_REM;
    else if (c == 0) state[v] = ST_CEN;
    else eCnt[v] = c;
}

__global__ __launch_bounds__(256) void k_compact(const int* __restrict__ state, const double* __restrict__ z,
                                                 double* __restrict__ cz, int* __restrict__ cidx,
                                                 int* counters) {
    int v = blockIdx.x * blockDim.x + threadIdx.x;
    if (v >= NN) return;
    if (state[v] == ST_CEN) {
        int slot = atomicAdd(&counters[0], 1);
        if (slot < CCAP) { cz[slot] = z[v]; cidx[slot] = v; }
    }
}

// Rank centers by (z desc, idx asc) via O(C^2) LDS-tiled counting.
__global__ __launch_bounds__(256) void k_rank(const double* __restrict__ cz, const int* __restrict__ cidx,
                                              const int* __restrict__ counters, int* __restrict__ cidOfNode) {
    __shared__ double tz[2048];
    __shared__ int ti[2048];
    int C = counters[0];
    if (C > CCAP) C = CCAP;
    int g = blockIdx.x * blockDim.x + threadIdx.x;
    bool mine = (g < C);
    double myz = 0.0;
    int myi = 0;
    if (mine) { myz = cz[g]; myi = cidx[g]; }
    int r = 0;
    for (int base = 0; base < C; base += 2048) {
        int tile = min(2048, C - base);
        for (int t = threadIdx.x; t < tile; t += blockDim.x) { tz[t] = cz[base + t]; ti[t] = cidx[base + t]; }
        __syncthreads();
        if (mine) {
            for (int t = 0; t < tile; ++t)
                if (earlier_f(tz[t], ti[t], myz, myi)) ++r;
        }
        __syncthreads();
    }
    if (mine && myi >= 0 && myi < NN) cidOfNode[myi] = r;
}

// Final cluster = latest-ranked center touching u (incl. self).
__global__ __launch_bounds__(256) void k_assign(const int* __restrict__ state, const double* __restrict__ z,
                                                const int* __restrict__ cnt, const int* __restrict__ inSrc,
                                                const int* __restrict__ cidOfNode, const int* __restrict__ batch,
                                                float* __restrict__ out_cl,
                                                float* __restrict__ out_ce, float* __restrict__ out_nb,
                                                int* __restrict__ mCount) {
    int u = blockIdx.x * blockDim.x + threadIdx.x;
    if (u >= NN) return;
    bool have = false;
    double bz = 0.0;
    int bi = -1;
    int stu = state[u];
    if (stu == ST_CEN) { have = true; bz = z[u]; bi = u; }
    int deg = min(cnt[u], IN_STR);
    size_t b = (size_t)u * IN_STR;
    for (int i = 0; i < deg; ++i) {
        int w = inSrc[b + i];
        if (state[w] != ST_CEN) continue;
        double zw = z[w];
        if (!have || earlier_f(bz, bi, zw, w)) { have = true; bz = zw; bi = w; }
    }
    int cl = have ? cidOfNode[bi] : 0;
    if (cl < 0) cl = 0;
    if (cl >= CCAP) cl = CCAP - 1;
    out_cl[u] = (float)cl;
    out_ce[u] = (stu == ST_CEN) ? 1.0f : 0.0f;
    out_nb[cl] = (float)batch[u];  // batch all-zero; benign same-value race
    atomicAdd(&mCount[cl], 1);
}

__global__ __launch_bounds__(1024) void k_scan(const int* __restrict__ in, int* __restrict__ out,
                                               int* __restrict__ cur, int n) {
    __shared__ int wsum[16];
    __shared__ int wpre[16];
    int tid = threadIdx.x, lane = tid & 63, wid = tid >> 6;
    int running = 0;
    for (int base = 0; base < n; base += 1024) {
        int i = base + tid;
        int v = (i < n) ? in[i] : 0;
        int incl = v;
        for (int off = 1; off < 64; off <<= 1) {
            int t = __shfl_up(incl, off);
            if (lane >= off) incl += t;
        }
        if (lane == 63) wsum[wid] = incl;
        __syncthreads();
        if (wid == 0 && lane < 16) {
            int s = wsum[lane];
            for (int off = 1; off < 16; off <<= 1) {
                int t = __shfl_up(s, off);
                if (lane >= off) s += t;
            }
            wpre[lane] = s - wsum[lane];
        }
        __syncthreads();
        int excl = running + wpre[wid] + incl - v;
        if (i < n) { out[i] = excl; if (cur) cur[i] = excl; }
        int tot = wpre[15] + wsum[15];
        running += tot;
        __syncthreads();
    }
    if (tid == 0) out[n] = running;
}

__global__ __launch_bounds__(256) void k_members(const float* __restrict__ out_cl, int* __restrict__ mCursor,
                                                 int* __restrict__ members) {
    int u = blockIdx.x * blockDim.x + threadIdx.x;
    if (u < NN) {
        int cl = (int)out_cl[u];
        if (cl < 0) cl = 0;
        if (cl >= CCAP) cl = CCAP - 1;
        int pos = atomicAdd(&mCursor[cl], 1);
        if (pos >= 0 && pos < NN) members[pos] = u;
    }
}

__global__ __launch_bounds__(256) void k_newx(const float* __restrict__ x, const int* __restrict__ mStart,
                                              const int* __restrict__ members, const int* __restrict__ counters,
                                              float* __restrict__ out_x) {
    int b = blockIdx.x;
    int t = threadIdx.x;
    int C = counters[0];
    if (C > CCAP) C = CCAP;
    double a0 = 0.0, a1 = 0.0;
    if (b < C) {
        int s = mStart[b], e = mStart[b + 1];
        for (int m = s; m < e; ++m) {
            const float* row = x + (size_t)members[m] * CIN;
            a0 += (double)row[t];
            a1 += (double)row[t + 256];
        }
    }
    out_x[(size_t)b * CIN + t] = (float)a0;
    out_x[(size_t)b * CIN + t + 256] = (float)a1;
}

__global__ __launch_bounds__(256) void k_edges(const int* __restrict__ src, const int* __restrict__ dst,
                                               const float* __restrict__ attr, const float* __restrict__ out_cl,
                                               float* __restrict__ out_ei, float* __restrict__ out_at) {
    int e = blockIdx.x * blockDim.x + threadIdx.x;
    if (e >= NE) return;
    int s = src[e], d = dst[e];
    float cs = (s >= 0 && s < NN) ? out_cl[s] : 0.0f;
    float cd = (d >= 0 && d < NN) ? out_cl[d] : 0.0f;
    out_ei[e] = cs;
    out_ei[NE + e] = cd;
    out_at[e] = attr[e];
}

__global__ void k_final(const int* counters, float* out_nc) {
    if (threadIdx.x == 0 && blockIdx.x == 0) {
        int C = counters[0];
        if (C > CCAP) C = CCAP;
        out_nc[0] = (float)C;
    }
}

extern "C" void kernel_launch(void* const* d_in, const int* in_sizes, int n_in,
                              void* d_out, int out_size, void* d_ws, size_t ws_size,
                              hipStream_t stream) {
    const float* x = (const float*)d_in[0];
    const int* ei = (const int*)d_in[1];
    const float* ea = (const float*)d_in[2];
    const int* batch = (const int*)d_in[3];
    const float* wrel = (const float*)d_in[4];
    const float* wroot = (const float*)d_in[5];
    const float* bptr = (const float*)d_in[6];
    float* out = (float*)d_out;
    (void)d_ws; (void)ws_size; (void)in_sizes; (void)n_in; (void)out_size;

    const int* src = ei;
    const int* dst = ei + NE;

    float* out_x = out;                                 // 25,600,000
    float* out_ei = out + (size_t)NN * CIN;             // 3,200,000
    float* out_at = out_ei + 2 * (size_t)NE;            // 1,600,000
    float* out_nb = out_at + (size_t)NE;                // 50,000
    float* out_cl = out_nb + NN;                        // 50,000
    float* out_ce = out_cl + NN;                        // 50,000
    float* out_nc = out_ce + NN;                        // 1

    // Scratch region 1: inside out_x (102.4 MB); all dead before k_newx overwrites it.
    char* r1 = (char*)out_x;
    size_t off1 = 0;
    auto alloc1 = [&](size_t bytes) -> void* {
        void* ptr = (void*)(r1 + off1);
        off1 = (off1 + bytes + 255) & ~(size_t)255;
        return ptr;
    };
    double* p_ = (double*)alloc1(NN * 8);
    double* z_ = (double*)alloc1(NN * 8);
    double* cz = (double*)alloc1(CCAP * 8);
    int* cnt = (int*)alloc1(NN * 4);
    int* state = (int*)alloc1(NN * 4);
    int* cidOfNode = (int*)alloc1(NN * 4);
    int* cidx = (int*)alloc1(CCAP * 4);
    int* eCnt = (int*)alloc1(NN * 4);
    int* inSrc = (int*)alloc1((size_t)NN * IN_STR * 4);  // 19.2 MB
    int* eNbr = (int*)alloc1((size_t)NN * E_STR * 4);    // 14.4 MB (total ~36 MB < 102 MB)

    // Scratch region 2: inside out_at (6.4 MB); dead before k_edges (last) overwrites it.
    char* r2 = (char*)out_at;
    size_t off2 = 0;
    auto alloc2 = [&](size_t bytes) -> void* {
        void* ptr = (void*)(r2 + off2);
        off2 = (off2 + bytes + 255) & ~(size_t)255;
        return ptr;
    };
    int* members = (int*)alloc2(NN * 4);
    int* mCount = (int*)alloc2(CCAP * 4);
    int* mStart = (int*)alloc2((CCAP + 1) * 4);
    int* mCursor = (int*)alloc2(CCAP * 4);
    int* counters = (int*)alloc2(64);

    hipMemsetAsync(cnt, 0, NN * 4, stream);
    hipMemsetAsync(state, 0, NN * 4, stream);
    hipMemsetAsync(mCount, 0, CCAP * 4, stream);
    hipMemsetAsync(counters, 0, 64, stream);
    hipMemsetAsync(out_nb, 0, NN * 4, stream);

    const int TB = 256;
    const int GN = (NN + TB - 1) / TB;   // 196
    const int GE = (NE + TB - 1) / TB;   // 6250

    k_rowdots<<<(NN * 64 + TB - 1) / TB, TB, 0, stream>>>(x, wrel, wroot, bptr, p_, z_);
    k_scatter<<<GE, TB, 0, stream>>>(src, dst, cnt, inSrc);
    k_zacc<<<GN, TB, 0, stream>>>(z_, p_, cnt, inSrc);
    k_prep<<<GN, TB, 0, stream>>>(z_, cnt, inSrc, eNbr, eCnt);

    // Fixpoint: gated ladder only. Kernel boundaries provide coherence; each
    // launch resolves >= 1 dependency level (depth < ~95 w.h.p.).
    for (int r = 0; r < N_SWEEP; ++r)
        k_fix_sweep<<<GN, TB, 0, stream>>>(z_, cnt, inSrc, eNbr, eCnt, state);

    k_compact<<<GN, TB, 0, stream>>>(state, z_, cz, cidx, counters);
    k_rank<<<CCAP / TB, TB, 0, stream>>>(cz, cidx, counters, cidOfNode);
    k_assign<<<GN, TB, 0, stream>>>(state, z_, cnt, inSrc, cidOfNode, batch,
                                    out_cl, out_ce, out_nb, mCount);
    k_scan<<<1, 1024, 0, stream>>>(mCount, mStart, mCursor, CCAP);
    k_members<<<GN, TB, 0, stream>>>(out_cl, mCursor, members);
    k_newx<<<NN, TB, 0, stream>>>(x, mStart, members, counters, out_x);   // kills region 1
    k_final<<<1, 64, 0, stream>>>(counters, out_nc);
    k_edges<<<GE, TB, 0, stream>>>(src, dst, ea, out_cl, out_ei, out_at); // kills region 2 (last)
}